// Round 9
// baseline (118.257 us; speedup 1.0000x reference)
//
#include <hip/hip_runtime.h>

// AdditiveAttention: B=4, Q=256, K=1024, DQ=DK=DV=512, H=128
#define B_ 4
#define Q_ 256
#define K_ 1024
#define D_ 512
#define H_ 128
#define DV_ 512
#define LOG2E 1.4426950408889634f

// tanh via exp2: tanh(x) = 1 - 2/(1+e^{2x}).  SUM_h w_h cancels in softmax:
// p = exp2( SUM_h (-2*log2e*w_h) * rcp(1 + eq*ek) ), eq/ek = exp2(SC*qh/kh)
// materialized in proj_reduce (r7, confirmed trans-bound: -3.8us).
//
// Round-9: r7 structure (best measured, 111.3us) + two retained/new deltas:
// (a) pairwise rcp in attn phase B (r8 math, strictly fewer trans at equal
//     VALU): acc += (w0*u1+w1*u0)*rcp(u0*u1), u = fma(eq,ek,1).
// (b) XCD-grouping block decode in attn (T1): all 32 qt-blocks sharing one
//     (b,kc) V-chunk (128KB) + kh-chunk (32KB) now land on ONE XCD
//     (XCD = bid&7 round-robin), so the chunk is fetched once into that
//     XCD's L2 instead of 8 L3-side fetches.  Pure bijection — perf-only.

// ---------------------------------------------------------------------------
// proj_part: tile = 32 rows x 128 h x 128 d (2 LDS chunks of 64 d).
// Grid 640 = [ds:4 == bid&3][tile:160 = 32 q + 128 k].  4 waves = h-quadrants,
// lane micro 4r x 4h.  40 KB LDS, XOR-swizzled transposed staging
// (write-conflict-free), next-chunk global loads overlap compute (T14).
// Epilogue: float4 partials -> psum[ds] (no atomics, no cross-block reduce).
// ---------------------------------------------------------------------------
__global__ __launch_bounds__(256) void proj_part(
    const float* __restrict__ qin, const float* __restrict__ kin,
    const float* __restrict__ wq,  const float* __restrict__ wk,
    const int* __restrict__ valid_lens, float* __restrict__ psum)
{
    __shared__ float Xs[64 * 32];    //  8 KB, [d][row],  col ^= ((d>>2)&7)<<2
    __shared__ float Ws[64 * 128];   // 32 KB, [d][h],    col ^= ((d>>2)&7)<<2

    const int t = threadIdx.x, bid = blockIdx.x;
    const int ds = bid & 3, tile = bid >> 2;     // tile 0..159
    const float* X; const float* W;
    int R0;
    if (tile < 32) { X = qin + (size_t)tile * 32 * D_; W = wq; R0 = tile * 32; }
    else {
        int kt = tile - 32, kb = kt >> 5, kr0 = (kt & 31) * 32;
        if (kr0 >= valid_lens[kb]) return;
        X = kin + ((size_t)kb * K_ + kr0) * D_;
        W = wk;
        R0 = 1024 + kt * 32;
    }

    const int xrow  = (t + 0) >> 4, xdq = (t & 15) * 4;
    const int xrow1 = (t + 256) >> 4;
    float4 xr0, xr1, wr8[8];

    #define LOADX(c) do { \
        xr0 = *(const float4*)&X[(size_t)xrow  * D_ + (c)*64 + xdq]; \
        xr1 = *(const float4*)&X[(size_t)xrow1 * D_ + (c)*64 + xdq]; } while (0)
    #define LOADW(c) do { \
        _Pragma("unroll") \
        for (int i = 0; i < 8; ++i) { \
            int idx = t + i * 256; \
            wr8[i] = *(const float4*)&W[(size_t)(idx >> 4) * D_ + (c)*64 + (idx & 15) * 4]; } } while (0)
    #define WRITE_LDS() do { \
        { float v[4]; *(float4*)v = xr0; \
          _Pragma("unroll") \
          for (int j = 0; j < 4; ++j) { int d = xdq + j; \
              Xs[d * 32 + (xrow ^ (((d >> 2) & 7) << 2))] = v[j]; } } \
        { float v[4]; *(float4*)v = xr1; \
          _Pragma("unroll") \
          for (int j = 0; j < 4; ++j) { int d = xdq + j; \
              Xs[d * 32 + (xrow1 ^ (((d >> 2) & 7) << 2))] = v[j]; } } \
        _Pragma("unroll") \
        for (int i = 0; i < 8; ++i) { \
            int idx = t + i * 256; int h = idx >> 4, dq = (idx & 15) * 4; \
            float v[4]; *(float4*)v = wr8[i]; \
            _Pragma("unroll") \
            for (int j = 0; j < 4; ++j) { int d = dq + j; \
                Ws[d * 128 + (h ^ (((d >> 2) & 7) << 2))] = v[j]; } } } while (0)

    const int wid = t >> 6, lane = t & 63;
    const int r0 = (lane & 7) * 4;                    // 4 rows
    const int h0 = wid * 32 + (lane >> 3) * 4;        // 4 h
    float c[4][4] = {};

    const int c0 = ds * 2;                            // 2 chunks: c0, c0+1
    LOADX(c0); LOADW(c0);
    WRITE_LDS();

    for (int cc = 0; cc < 2; ++cc) {
        __syncthreads();                  // LDS chunk ready
        if (cc < 1) { LOADX(c0 + 1); LOADW(c0 + 1); }
#pragma unroll 8
        for (int kk = 0; kk < 64; ++kk) {
            const int xc = ((kk >> 2) & 7) << 2;
            float xr[4], wr[4];
            *(float4*)&xr[0] = *(const float4*)&Xs[kk * 32  + (r0 ^ xc)];
            *(float4*)&wr[0] = *(const float4*)&Ws[kk * 128 + (h0 ^ xc)];
#pragma unroll
            for (int i = 0; i < 4; ++i)
#pragma unroll
                for (int j = 0; j < 4; ++j) c[i][j] = fmaf(xr[i], wr[j], c[i][j]);
        }
        __syncthreads();                  // all reads done
        if (cc < 1) WRITE_LDS();
    }

    float* outp = psum + ((size_t)ds * 5120 + R0) * 128;
#pragma unroll
    for (int i = 0; i < 4; ++i)
        *(float4*)&outp[(size_t)(r0 + i) * 128 + h0] = *(const float4*)&c[i][0];

    #undef LOADX
    #undef LOADW
    #undef WRITE_LDS
}

// ---------------------------------------------------------------------------
// proj_reduce: sum 4 d-slices, then store eq = exp2(2*log2e * qh) and
// ek = exp2(2*log2e * kh)  (factored inner exponentials).  Grid 640.
// ---------------------------------------------------------------------------
__global__ __launch_bounds__(256) void proj_reduce(
    const float* __restrict__ psum, const int* __restrict__ valid_lens,
    float* __restrict__ qh_s, float4* __restrict__ kh4)
{
    int gid = blockIdx.x * 256 + threadIdx.x;    // [0, 163840)
    int row = gid >> 5, c4 = gid & 31;
    int b = 0, kk = 0;
    if (row >= 1024) {
        int r = row - 1024;
        b = r >> 10; kk = r & 1023;
        if (kk >= valid_lens[b]) return;
    }
    float4 s = make_float4(0.f, 0.f, 0.f, 0.f);
#pragma unroll
    for (int ds = 0; ds < 4; ++ds) {
        float4 v = *(const float4*)&psum[((size_t)ds * 5120 + row) * 128 + c4 * 4];
        s.x += v.x; s.y += v.y; s.z += v.z; s.w += v.w;
    }
    const float SC = 2.0f * LOG2E;
    s.x = __builtin_amdgcn_exp2f(s.x * SC);
    s.y = __builtin_amdgcn_exp2f(s.y * SC);
    s.z = __builtin_amdgcn_exp2f(s.z * SC);
    s.w = __builtin_amdgcn_exp2f(s.w * SC);
    if (row < 1024) *(float4*)&qh_s[(size_t)row * 128 + c4 * 4] = s;
    else            kh4[((size_t)(b * 32 + c4)) * K_ + kk] = s;
}

// ---------------------------------------------------------------------------
// attn_part: 2048 blocks x 256 thr (4 waves), item = (b, 8-q tile, 64-k
// chunk); ~1024 active.  LDS ~14.6 KB.
// Decode (XCD-grouped, T1): s = bid&7 (XCD), j = bid>>3, qt = j&31,
// g = s + (j>>5)*8, kc = g&15, b = g>>4 — the 32 qt-blocks of a (b,kc)
// group share one XCD so V/kh chunks are L2-resident (fetched once/XCD).
// Phase B: 4-way h-split, ek prefetch depth 1, pairwise sigmoid:
//   u = fma(eq,ek,1);  acc += (w0*u1 + w1*u0) * rcp(u0*u1)
// = 3 VALU + 0.5 trans / elem.  Combine: all 4 waves, 2 q-rows each.
// Phase D: per-thread float2 column (256 cols) x 8 q-rows x full klen.
// ---------------------------------------------------------------------------
__global__ __launch_bounds__(256) void attn_part(
    const float* __restrict__ qh_s, const float4* __restrict__ kh4,
    const float* __restrict__ wvg,  const int* __restrict__ valid_lens,
    const float* __restrict__ vin,
    float* __restrict__ s_part, float* __restrict__ o_part)
{
    __shared__ float  qv[1024];
    __shared__ float  wvs[128];
    __shared__ float  ptmp[4][8][64];
    __shared__ float  p[8][64];
    __shared__ float  sred[8];

    const int t   = threadIdx.x;
    const int bid = blockIdx.x;
    const int xs  = bid & 7;            // XCD slot (round-robin dispatch)
    const int j   = bid >> 3;
    const int qt  = j & 31;
    const int g   = xs + (j >> 5) * 8;  // group 0..63
    const int kc  = g & 15, b = g >> 4;
    const int q0  = qt * 8;
    const int vl  = valid_lens[b];
    const int kbase = kc * 64;
    if (kbase >= vl) return;
    const int klen = min(64, vl - kbase);

#pragma unroll
    for (int i = 0; i < 4; ++i)
        qv[t + i * 256] = qh_s[(size_t)(b*Q_ + q0) * H_ + t + i * 256];
    if (t < 128) wvs[t] = wvg[t] * (-2.0f * LOG2E);
    __syncthreads();

    const int k  = t & 63;              // k within chunk
    const int hh = t >> 6;              // h-quarter (== wave id)
    const bool active = k < klen;

    // ---- Phase B: scores (4-way h-split, ek prefetch depth 1) ----
    float acc[8] = {};
    if (active) {
        const float4* khp = kh4 + (size_t)b * 32 * K_ + (kbase + k)
                          + (size_t)(hh * 8) * K_;
        const int hq0 = hh * 8;
        float4 kxn = khp[0];
#pragma unroll
        for (int i = 0; i < 8; ++i) {
            float4 kx = kxn;
            int ni = (i < 7) ? i + 1 : 7;
            kxn = khp[(size_t)ni * K_];
            const int hq = hq0 + i;
            float w4[4], kxa[4];
            *(float4*)&w4[0]  = *(const float4*)&wvs[hq*4];
            *(float4*)&kxa[0] = kx;
#pragma unroll
            for (int qi = 0; qi < 8; ++qi) {
                float q4[4];
                *(float4*)&q4[0] = *(const float4*)&qv[qi*128 + hq*4];
                float u0 = fmaf(q4[0], kxa[0], 1.0f);
                float u1 = fmaf(q4[1], kxa[1], 1.0f);
                float u2 = fmaf(q4[2], kxa[2], 1.0f);
                float u3 = fmaf(q4[3], kxa[3], 1.0f);
                float n01 = fmaf(w4[0], u1, w4[1] * u0);
                float n23 = fmaf(w4[2], u3, w4[3] * u2);
                float r01 = __builtin_amdgcn_rcpf(u0 * u1);
                float r23 = __builtin_amdgcn_rcpf(u2 * u3);
                acc[qi] = fmaf(n01, r01, acc[qi]);
                acc[qi] = fmaf(n23, r23, acc[qi]);
            }
        }
    }
#pragma unroll
    for (int qi = 0; qi < 8; ++qi) ptmp[hh][qi][k] = acc[qi];
    __syncthreads();

    // ---- combine: each wave finishes 2 q-rows ----
    {
        const int qia = hh * 2;
#pragma unroll
        for (int q2 = 0; q2 < 2; ++q2) {
            const int qi = qia + q2;
            float a = ptmp[0][qi][k] + ptmp[1][qi][k]
                    + ptmp[2][qi][k] + ptmp[3][qi][k];
            // a is already log2(p) (all scale factors folded upstream)
            float e = active ? __builtin_amdgcn_exp2f(a) : 0.f;
            p[qi][k] = e;
            float s = e;
#pragma unroll
            for (int off = 32; off > 0; off >>= 1) s += __shfl_xor(s, off);
            if (k == 0) sred[qi] = s;
        }
    }
    __syncthreads();                    // p + sred ready

    if (t < 8)
        s_part[(size_t)(b*Q_ + q0 + t) * 16 + kc] = sred[t];

    // ---- Phase D: partial PV (float2 col per thread, full klen) ----
    const int col2 = t;                 // float2 column 0..255
    const float2* vb2 = (const float2*)vin + ((size_t)b * K_ + kbase) * 256;

    float2 o[8];
#pragma unroll
    for (int qi = 0; qi < 8; ++qi) o[qi] = make_float2(0.f, 0.f);

    int kk = 0;
    const int nfull = klen >> 2;
    if (nfull > 0) {
        float2 n0v = vb2[(size_t)0 * 256 + col2];
        float2 n1v = vb2[(size_t)1 * 256 + col2];
        float2 n2v = vb2[(size_t)2 * 256 + col2];
        float2 n3v = vb2[(size_t)3 * 256 + col2];
        for (int g2 = 0; g2 < nfull; ++g2) {
            float2 v0 = n0v, v1 = n1v, v2 = n2v, v3 = n3v;
            int kn = kk + 4;
            if (g2 + 1 < nfull) {
                n0v = vb2[(size_t)(kn+0)*256 + col2];
                n1v = vb2[(size_t)(kn+1)*256 + col2];
                n2v = vb2[(size_t)(kn+2)*256 + col2];
                n3v = vb2[(size_t)(kn+3)*256 + col2];
            }
#pragma unroll
            for (int qi = 0; qi < 8; ++qi) {
                float4 pq = *(const float4*)&p[qi][kk];   // uniform -> broadcast
                o[qi].x += pq.x*v0.x + pq.y*v1.x + pq.z*v2.x + pq.w*v3.x;
                o[qi].y += pq.x*v0.y + pq.y*v1.y + pq.z*v2.y + pq.w*v3.y;
            }
            kk = kn;
        }
    }
    for (; kk < klen; ++kk) {
        float2 v0 = vb2[(size_t)kk*256 + col2];
#pragma unroll
        for (int qi = 0; qi < 8; ++qi) {
            float pk = p[qi][kk];
            o[qi].x += pk*v0.x; o[qi].y += pk*v0.y;
        }
    }

#pragma unroll
    for (int qi = 0; qi < 8; ++qi) {
        size_t row = (size_t)b*Q_ + q0 + qi;
        *(float2*)&o_part[((size_t)kc * 1024 + row) * 512 + col2 * 2] = o[qi];
    }
}

// ---------------------------------------------------------------------------
// finalize: out[row][col] = (Sum_{ch<nch} o_part[ch][row][col]) * rcp(Sum s).
// nch = ceil(vl/64) <= 16.
// ---------------------------------------------------------------------------
__global__ __launch_bounds__(256) void finalize_kernel(
    const float4* __restrict__ o_part, const float* __restrict__ s_part,
    const int* __restrict__ valid_lens, float4* __restrict__ out)
{
    int gid = blockIdx.x * 256 + threadIdx.x;     // [0, 131072)
    int row = gid >> 7, col = gid & 127;
    int b = row >> 8;
    int nch = (valid_lens[b] + 63) >> 6;
    float ssum = 0.f;
    float4 o = make_float4(0.f, 0.f, 0.f, 0.f);
    for (int ch = 0; ch < nch; ++ch) {
        ssum += s_part[(size_t)row * 16 + ch];
        float4 r = o_part[((size_t)ch * 1024 + row) * 128 + col];
        o.x += r.x; o.y += r.y; o.z += r.z; o.w += r.w;
    }
    float rs = __builtin_amdgcn_rcpf(ssum);
    out[gid] = make_float4(o.x*rs, o.y*rs, o.z*rs, o.w*rs);
}

extern "C" void kernel_launch(void* const* d_in, const int* in_sizes, int n_in,
                              void* d_out, int out_size, void* d_ws, size_t ws_size,
                              hipStream_t stream)
{
    const float* q  = (const float*)d_in[0];
    const float* k  = (const float*)d_in[1];
    const float* v  = (const float*)d_in[2];
    const int*   vl = (const int*)d_in[3];
    const float* wq = (const float*)d_in[4];
    const float* wk = (const float*)d_in[5];
    const float* wv = (const float*)d_in[6];
    float* out = (float*)d_out;

    float* qh_s  = (float*)d_ws;                      //  131072 f
    float* kh4   = qh_s  + (size_t)B_*Q_*H_;          //  524288 f
    float* s_prt = kh4   + (size_t)B_*H_*K_;          //   16384 f
    float* o_prt = s_prt + (size_t)B_*Q_*16;          // 8388608 f (32 MB)
    float* psum  = o_prt + (size_t)16*B_*Q_*DV_;      // 2621440 f (10.5 MB)

    proj_part      <<<dim3(640),  dim3(256), 0, stream>>>(q, k, wq, wk, vl, psum);
    proj_reduce    <<<dim3(640),  dim3(256), 0, stream>>>(psum, vl, qh_s, (float4*)kh4);
    attn_part      <<<dim3(2048), dim3(256), 0, stream>>>(qh_s, (const float4*)kh4, wv, vl, v, s_prt, o_prt);
    finalize_kernel<<<dim3(512),  dim3(256), 0, stream>>>((const float4*)o_prt, s_prt, vl, (float4*)out);
}

// Round 10
// 114.477 us; speedup vs baseline: 1.0330x; 1.0330x over previous
//
#include <hip/hip_runtime.h>

// AdditiveAttention: B=4, Q=256, K=1024, DQ=DK=DV=512, H=128
#define B_ 4
#define Q_ 256
#define K_ 1024
#define D_ 512
#define H_ 128
#define DV_ 512
#define LOG2E 1.4426950408889634f

// tanh via exp2: tanh(x) = 1 - 2/(1+e^{2x}).  SUM_h w_h cancels in softmax:
// p = exp2( SUM_h (-2*log2e*w_h) * rcp(1 + eq*ek) ), eq/ek = exp2(SC*qh/kh)
// materialized in proj_reduce (r7, confirmed trans-bound: -3.8us).
//
// Round-10: SINGLE-VARIABLE test.  Exactly the r7 kernel (best measured,
// 111.3us; original block decode, proj 32x128) with ONE change: pairwise
// rcp in attn phase B —  w0/u0 + w1/u1 = (w0*u1+w1*u0)*rcp(u0*u1),
// u = fma(eq,ek,1) >= 1.  3 VALU + 0.5 trans / elem (r7: 3 + 1).
// r8/r9 bundled this with proj-retile / XCD-decode which both regressed;
// this isolates it.  (r9 lesson: XCD grouping under heavy masking
// unbalances active work — default dispatch locality was already fine.)

// ---------------------------------------------------------------------------
// proj_part: tile = 32 rows x 128 h x 128 d (2 LDS chunks of 64 d).
// Grid 640 = [ds:4 == bid&3][tile:160 = 32 q + 128 k].  4 waves = h-quadrants,
// lane micro 4r x 4h.  40 KB LDS, XOR-swizzled transposed staging
// (write-conflict-free), next-chunk global loads overlap compute (T14).
// Epilogue: float4 partials -> psum[ds] (no atomics, no cross-block reduce).
// ---------------------------------------------------------------------------
__global__ __launch_bounds__(256) void proj_part(
    const float* __restrict__ qin, const float* __restrict__ kin,
    const float* __restrict__ wq,  const float* __restrict__ wk,
    const int* __restrict__ valid_lens, float* __restrict__ psum)
{
    __shared__ float Xs[64 * 32];    //  8 KB, [d][row],  col ^= ((d>>2)&7)<<2
    __shared__ float Ws[64 * 128];   // 32 KB, [d][h],    col ^= ((d>>2)&7)<<2

    const int t = threadIdx.x, bid = blockIdx.x;
    const int ds = bid & 3, tile = bid >> 2;     // tile 0..159
    const float* X; const float* W;
    int R0;
    if (tile < 32) { X = qin + (size_t)tile * 32 * D_; W = wq; R0 = tile * 32; }
    else {
        int kt = tile - 32, kb = kt >> 5, kr0 = (kt & 31) * 32;
        if (kr0 >= valid_lens[kb]) return;
        X = kin + ((size_t)kb * K_ + kr0) * D_;
        W = wk;
        R0 = 1024 + kt * 32;
    }

    const int xrow  = (t + 0) >> 4, xdq = (t & 15) * 4;
    const int xrow1 = (t + 256) >> 4;
    float4 xr0, xr1, wr8[8];

    #define LOADX(c) do { \
        xr0 = *(const float4*)&X[(size_t)xrow  * D_ + (c)*64 + xdq]; \
        xr1 = *(const float4*)&X[(size_t)xrow1 * D_ + (c)*64 + xdq]; } while (0)
    #define LOADW(c) do { \
        _Pragma("unroll") \
        for (int i = 0; i < 8; ++i) { \
            int idx = t + i * 256; \
            wr8[i] = *(const float4*)&W[(size_t)(idx >> 4) * D_ + (c)*64 + (idx & 15) * 4]; } } while (0)
    #define WRITE_LDS() do { \
        { float v[4]; *(float4*)v = xr0; \
          _Pragma("unroll") \
          for (int j = 0; j < 4; ++j) { int d = xdq + j; \
              Xs[d * 32 + (xrow ^ (((d >> 2) & 7) << 2))] = v[j]; } } \
        { float v[4]; *(float4*)v = xr1; \
          _Pragma("unroll") \
          for (int j = 0; j < 4; ++j) { int d = xdq + j; \
              Xs[d * 32 + (xrow1 ^ (((d >> 2) & 7) << 2))] = v[j]; } } \
        _Pragma("unroll") \
        for (int i = 0; i < 8; ++i) { \
            int idx = t + i * 256; int h = idx >> 4, dq = (idx & 15) * 4; \
            float v[4]; *(float4*)v = wr8[i]; \
            _Pragma("unroll") \
            for (int j = 0; j < 4; ++j) { int d = dq + j; \
                Ws[d * 128 + (h ^ (((d >> 2) & 7) << 2))] = v[j]; } } } while (0)

    const int wid = t >> 6, lane = t & 63;
    const int r0 = (lane & 7) * 4;                    // 4 rows
    const int h0 = wid * 32 + (lane >> 3) * 4;        // 4 h
    float c[4][4] = {};

    const int c0 = ds * 2;                            // 2 chunks: c0, c0+1
    LOADX(c0); LOADW(c0);
    WRITE_LDS();

    for (int cc = 0; cc < 2; ++cc) {
        __syncthreads();                  // LDS chunk ready
        if (cc < 1) { LOADX(c0 + 1); LOADW(c0 + 1); }
#pragma unroll 8
        for (int kk = 0; kk < 64; ++kk) {
            const int xc = ((kk >> 2) & 7) << 2;
            float xr[4], wr[4];
            *(float4*)&xr[0] = *(const float4*)&Xs[kk * 32  + (r0 ^ xc)];
            *(float4*)&wr[0] = *(const float4*)&Ws[kk * 128 + (h0 ^ xc)];
#pragma unroll
            for (int i = 0; i < 4; ++i)
#pragma unroll
                for (int j = 0; j < 4; ++j) c[i][j] = fmaf(xr[i], wr[j], c[i][j]);
        }
        __syncthreads();                  // all reads done
        if (cc < 1) WRITE_LDS();
    }

    float* outp = psum + ((size_t)ds * 5120 + R0) * 128;
#pragma unroll
    for (int i = 0; i < 4; ++i)
        *(float4*)&outp[(size_t)(r0 + i) * 128 + h0] = *(const float4*)&c[i][0];

    #undef LOADX
    #undef LOADW
    #undef WRITE_LDS
}

// ---------------------------------------------------------------------------
// proj_reduce: sum 4 d-slices, then store eq = exp2(2*log2e * qh) and
// ek = exp2(2*log2e * kh)  (factored inner exponentials).  Grid 640.
// ---------------------------------------------------------------------------
__global__ __launch_bounds__(256) void proj_reduce(
    const float* __restrict__ psum, const int* __restrict__ valid_lens,
    float* __restrict__ qh_s, float4* __restrict__ kh4)
{
    int gid = blockIdx.x * 256 + threadIdx.x;    // [0, 163840)
    int row = gid >> 5, c4 = gid & 31;
    int b = 0, kk = 0;
    if (row >= 1024) {
        int r = row - 1024;
        b = r >> 10; kk = r & 1023;
        if (kk >= valid_lens[b]) return;
    }
    float4 s = make_float4(0.f, 0.f, 0.f, 0.f);
#pragma unroll
    for (int ds = 0; ds < 4; ++ds) {
        float4 v = *(const float4*)&psum[((size_t)ds * 5120 + row) * 128 + c4 * 4];
        s.x += v.x; s.y += v.y; s.z += v.z; s.w += v.w;
    }
    const float SC = 2.0f * LOG2E;
    s.x = __builtin_amdgcn_exp2f(s.x * SC);
    s.y = __builtin_amdgcn_exp2f(s.y * SC);
    s.z = __builtin_amdgcn_exp2f(s.z * SC);
    s.w = __builtin_amdgcn_exp2f(s.w * SC);
    if (row < 1024) *(float4*)&qh_s[(size_t)row * 128 + c4 * 4] = s;
    else            kh4[((size_t)(b * 32 + c4)) * K_ + kk] = s;
}

// ---------------------------------------------------------------------------
// attn_part: 2048 blocks x 256 thr (4 waves), item = (b, 8-q tile, 64-k
// chunk); ~1024 active.  LDS ~14.6 KB.  Original decode (qt = bid&31).
// Phase B: 4-way h-split, ek prefetch depth 1, pairwise sigmoid:
//   u = fma(eq,ek,1);  acc += (w0*u1 + w1*u0) * rcp(u0*u1)
// = 3 VALU + 0.5 trans / elem.  Combine: all 4 waves, 2 q-rows each.
// Phase D: per-thread float2 column (256 cols) x 8 q-rows x full klen.
// ---------------------------------------------------------------------------
__global__ __launch_bounds__(256) void attn_part(
    const float* __restrict__ qh_s, const float4* __restrict__ kh4,
    const float* __restrict__ wvg,  const int* __restrict__ valid_lens,
    const float* __restrict__ vin,
    float* __restrict__ s_part, float* __restrict__ o_part)
{
    __shared__ float  qv[1024];
    __shared__ float  wvs[128];
    __shared__ float  ptmp[4][8][64];
    __shared__ float  p[8][64];
    __shared__ float  sred[8];

    const int t   = threadIdx.x;
    const int bid = blockIdx.x;
    const int qt  = bid & 31, kc = (bid >> 5) & 15, b = bid >> 9;
    const int q0  = qt * 8;
    const int vl  = valid_lens[b];
    const int kbase = kc * 64;
    if (kbase >= vl) return;
    const int klen = min(64, vl - kbase);

#pragma unroll
    for (int i = 0; i < 4; ++i)
        qv[t + i * 256] = qh_s[(size_t)(b*Q_ + q0) * H_ + t + i * 256];
    if (t < 128) wvs[t] = wvg[t] * (-2.0f * LOG2E);
    __syncthreads();

    const int k  = t & 63;              // k within chunk
    const int hh = t >> 6;              // h-quarter (== wave id)
    const bool active = k < klen;

    // ---- Phase B: scores (4-way h-split, ek prefetch depth 1) ----
    float acc[8] = {};
    if (active) {
        const float4* khp = kh4 + (size_t)b * 32 * K_ + (kbase + k)
                          + (size_t)(hh * 8) * K_;
        const int hq0 = hh * 8;
        float4 kxn = khp[0];
#pragma unroll
        for (int i = 0; i < 8; ++i) {
            float4 kx = kxn;
            int ni = (i < 7) ? i + 1 : 7;
            kxn = khp[(size_t)ni * K_];
            const int hq = hq0 + i;
            float w4[4], kxa[4];
            *(float4*)&w4[0]  = *(const float4*)&wvs[hq*4];
            *(float4*)&kxa[0] = kx;
#pragma unroll
            for (int qi = 0; qi < 8; ++qi) {
                float q4[4];
                *(float4*)&q4[0] = *(const float4*)&qv[qi*128 + hq*4];
                float u0 = fmaf(q4[0], kxa[0], 1.0f);
                float u1 = fmaf(q4[1], kxa[1], 1.0f);
                float u2 = fmaf(q4[2], kxa[2], 1.0f);
                float u3 = fmaf(q4[3], kxa[3], 1.0f);
                float n01 = fmaf(w4[0], u1, w4[1] * u0);
                float n23 = fmaf(w4[2], u3, w4[3] * u2);
                float r01 = __builtin_amdgcn_rcpf(u0 * u1);
                float r23 = __builtin_amdgcn_rcpf(u2 * u3);
                acc[qi] = fmaf(n01, r01, acc[qi]);
                acc[qi] = fmaf(n23, r23, acc[qi]);
            }
        }
    }
#pragma unroll
    for (int qi = 0; qi < 8; ++qi) ptmp[hh][qi][k] = acc[qi];
    __syncthreads();

    // ---- combine: each wave finishes 2 q-rows ----
    {
        const int qia = hh * 2;
#pragma unroll
        for (int q2 = 0; q2 < 2; ++q2) {
            const int qi = qia + q2;
            float a = ptmp[0][qi][k] + ptmp[1][qi][k]
                    + ptmp[2][qi][k] + ptmp[3][qi][k];
            // a is already log2(p) (all scale factors folded upstream)
            float e = active ? __builtin_amdgcn_exp2f(a) : 0.f;
            p[qi][k] = e;
            float s = e;
#pragma unroll
            for (int off = 32; off > 0; off >>= 1) s += __shfl_xor(s, off);
            if (k == 0) sred[qi] = s;
        }
    }
    __syncthreads();                    // p + sred ready

    if (t < 8)
        s_part[(size_t)(b*Q_ + q0 + t) * 16 + kc] = sred[t];

    // ---- Phase D: partial PV (float2 col per thread, full klen) ----
    const int col2 = t;                 // float2 column 0..255
    const float2* vb2 = (const float2*)vin + ((size_t)b * K_ + kbase) * 256;

    float2 o[8];
#pragma unroll
    for (int qi = 0; qi < 8; ++qi) o[qi] = make_float2(0.f, 0.f);

    int kk = 0;
    const int nfull = klen >> 2;
    if (nfull > 0) {
        float2 n0v = vb2[(size_t)0 * 256 + col2];
        float2 n1v = vb2[(size_t)1 * 256 + col2];
        float2 n2v = vb2[(size_t)2 * 256 + col2];
        float2 n3v = vb2[(size_t)3 * 256 + col2];
        for (int g = 0; g < nfull; ++g) {
            float2 v0 = n0v, v1 = n1v, v2 = n2v, v3 = n3v;
            int kn = kk + 4;
            if (g + 1 < nfull) {
                n0v = vb2[(size_t)(kn+0)*256 + col2];
                n1v = vb2[(size_t)(kn+1)*256 + col2];
                n2v = vb2[(size_t)(kn+2)*256 + col2];
                n3v = vb2[(size_t)(kn+3)*256 + col2];
            }
#pragma unroll
            for (int qi = 0; qi < 8; ++qi) {
                float4 pq = *(const float4*)&p[qi][kk];   // uniform -> broadcast
                o[qi].x += pq.x*v0.x + pq.y*v1.x + pq.z*v2.x + pq.w*v3.x;
                o[qi].y += pq.x*v0.y + pq.y*v1.y + pq.z*v2.y + pq.w*v3.y;
            }
            kk = kn;
        }
    }
    for (; kk < klen; ++kk) {
        float2 v0 = vb2[(size_t)kk*256 + col2];
#pragma unroll
        for (int qi = 0; qi < 8; ++qi) {
            float pk = p[qi][kk];
            o[qi].x += pk*v0.x; o[qi].y += pk*v0.y;
        }
    }

#pragma unroll
    for (int qi = 0; qi < 8; ++qi) {
        size_t row = (size_t)b*Q_ + q0 + qi;
        *(float2*)&o_part[((size_t)kc * 1024 + row) * 512 + col2 * 2] = o[qi];
    }
}

// ---------------------------------------------------------------------------
// finalize: out[row][col] = (Sum_{ch<nch} o_part[ch][row][col]) * rcp(Sum s).
// nch = ceil(vl/64) <= 16.
// ---------------------------------------------------------------------------
__global__ __launch_bounds__(256) void finalize_kernel(
    const float4* __restrict__ o_part, const float* __restrict__ s_part,
    const int* __restrict__ valid_lens, float4* __restrict__ out)
{
    int gid = blockIdx.x * 256 + threadIdx.x;     // [0, 131072)
    int row = gid >> 7, col = gid & 127;
    int b = row >> 8;
    int nch = (valid_lens[b] + 63) >> 6;
    float ssum = 0.f;
    float4 o = make_float4(0.f, 0.f, 0.f, 0.f);
    for (int ch = 0; ch < nch; ++ch) {
        ssum += s_part[(size_t)row * 16 + ch];
        float4 r = o_part[((size_t)ch * 1024 + row) * 128 + col];
        o.x += r.x; o.y += r.y; o.z += r.z; o.w += r.w;
    }
    float rs = __builtin_amdgcn_rcpf(ssum);
    out[gid] = make_float4(o.x*rs, o.y*rs, o.z*rs, o.w*rs);
}

extern "C" void kernel_launch(void* const* d_in, const int* in_sizes, int n_in,
                              void* d_out, int out_size, void* d_ws, size_t ws_size,
                              hipStream_t stream)
{
    const float* q  = (const float*)d_in[0];
    const float* k  = (const float*)d_in[1];
    const float* v  = (const float*)d_in[2];
    const int*   vl = (const int*)d_in[3];
    const float* wq = (const float*)d_in[4];
    const float* wk = (const float*)d_in[5];
    const float* wv = (const float*)d_in[6];
    float* out = (float*)d_out;

    float* qh_s  = (float*)d_ws;                      //  131072 f
    float* kh4   = qh_s  + (size_t)B_*Q_*H_;          //  524288 f
    float* s_prt = kh4   + (size_t)B_*H_*K_;          //   16384 f
    float* o_prt = s_prt + (size_t)B_*Q_*16;          // 8388608 f (32 MB)
    float* psum  = o_prt + (size_t)16*B_*Q_*DV_;      // 2621440 f (10.5 MB)

    proj_part      <<<dim3(640),  dim3(256), 0, stream>>>(q, k, wq, wk, vl, psum);
    proj_reduce    <<<dim3(640),  dim3(256), 0, stream>>>(psum, vl, qh_s, (float4*)kh4);
    attn_part      <<<dim3(2048), dim3(256), 0, stream>>>(qh_s, (const float4*)kh4, wv, vl, v, s_prt, o_prt);
    finalize_kernel<<<dim3(512),  dim3(256), 0, stream>>>((const float4*)o_prt, s_prt, vl, (float4*)out);
}

// Round 11
// 112.036 us; speedup vs baseline: 1.0555x; 1.0218x over previous
//
#include <hip/hip_runtime.h>

// AdditiveAttention: B=4, Q=256, K=1024, DQ=DK=DV=512, H=128
#define B_ 4
#define Q_ 256
#define K_ 1024
#define D_ 512
#define H_ 128
#define DV_ 512
#define LOG2E 1.4426950408889634f

// FINAL (r11 = r7 verbatim, the measured optimum: 111.3us).
// tanh via exp2: tanh(x) = 1 - 2/(1+e^{2x}).  SUM_h w_h cancels in softmax:
// p = exp2( SUM_h (-2*log2e*w_h) * rcp(1 + eq*ek) ), with the factored
// exponentials eq = exp2(SC*qh), ek = exp2(SC*kh) materialized once in
// proj_reduce (655k trans ops) instead of 67M times in attn.
// attn phase B inner: {mul, add, rcp, fma} = 3 VALU + 1 trans / element.
//
// Session ledger (what moved the needle and what didn't):
//   WIN  exp2-tanh vs Pade (-5.3us), exp2 factoring (-3.8us)
//   NULL psum traffic halving (r4), attn LDS/occupancy trim (r6)
//   LOSS dense f32 atomics (r2: +178us), low-parallelism grids (r3: +46),
//        last-arrival fences in 2048-blk kernel (r5: +59), proj 64x64
//        retile (r8: +2), XCD-grouped decode under masking (r9: +7),
//        pairwise rcp (r10: +3, longer dep chain beats trans savings).
// Regime: latency/parallelism-bound chain (~27us) inside a fill-dominated
// timed window; both pipe-floor math levers are banked here.

// ---------------------------------------------------------------------------
// proj_part: tile = 32 rows x 128 h x 128 d (2 LDS chunks of 64 d).
// Grid 640 = [ds:4 == bid&3][tile:160 = 32 q + 128 k].  4 waves = h-quadrants,
// lane micro 4r x 4h.  40 KB LDS, XOR-swizzled transposed staging
// (write-conflict-free), next-chunk global loads overlap compute (T14).
// Epilogue: float4 partials -> psum[ds] (no atomics, no cross-block reduce).
// ---------------------------------------------------------------------------
__global__ __launch_bounds__(256) void proj_part(
    const float* __restrict__ qin, const float* __restrict__ kin,
    const float* __restrict__ wq,  const float* __restrict__ wk,
    const int* __restrict__ valid_lens, float* __restrict__ psum)
{
    __shared__ float Xs[64 * 32];    //  8 KB, [d][row],  col ^= ((d>>2)&7)<<2
    __shared__ float Ws[64 * 128];   // 32 KB, [d][h],    col ^= ((d>>2)&7)<<2

    const int t = threadIdx.x, bid = blockIdx.x;
    const int ds = bid & 3, tile = bid >> 2;     // tile 0..159
    const float* X; const float* W;
    int R0;
    if (tile < 32) { X = qin + (size_t)tile * 32 * D_; W = wq; R0 = tile * 32; }
    else {
        int kt = tile - 32, kb = kt >> 5, kr0 = (kt & 31) * 32;
        if (kr0 >= valid_lens[kb]) return;
        X = kin + ((size_t)kb * K_ + kr0) * D_;
        W = wk;
        R0 = 1024 + kt * 32;
    }

    const int xrow  = (t + 0) >> 4, xdq = (t & 15) * 4;
    const int xrow1 = (t + 256) >> 4;
    float4 xr0, xr1, wr8[8];

    #define LOADX(c) do { \
        xr0 = *(const float4*)&X[(size_t)xrow  * D_ + (c)*64 + xdq]; \
        xr1 = *(const float4*)&X[(size_t)xrow1 * D_ + (c)*64 + xdq]; } while (0)
    #define LOADW(c) do { \
        _Pragma("unroll") \
        for (int i = 0; i < 8; ++i) { \
            int idx = t + i * 256; \
            wr8[i] = *(const float4*)&W[(size_t)(idx >> 4) * D_ + (c)*64 + (idx & 15) * 4]; } } while (0)
    #define WRITE_LDS() do { \
        { float v[4]; *(float4*)v = xr0; \
          _Pragma("unroll") \
          for (int j = 0; j < 4; ++j) { int d = xdq + j; \
              Xs[d * 32 + (xrow ^ (((d >> 2) & 7) << 2))] = v[j]; } } \
        { float v[4]; *(float4*)v = xr1; \
          _Pragma("unroll") \
          for (int j = 0; j < 4; ++j) { int d = xdq + j; \
              Xs[d * 32 + (xrow1 ^ (((d >> 2) & 7) << 2))] = v[j]; } } \
        _Pragma("unroll") \
        for (int i = 0; i < 8; ++i) { \
            int idx = t + i * 256; int h = idx >> 4, dq = (idx & 15) * 4; \
            float v[4]; *(float4*)v = wr8[i]; \
            _Pragma("unroll") \
            for (int j = 0; j < 4; ++j) { int d = dq + j; \
                Ws[d * 128 + (h ^ (((d >> 2) & 7) << 2))] = v[j]; } } } while (0)

    const int wid = t >> 6, lane = t & 63;
    const int r0 = (lane & 7) * 4;                    // 4 rows
    const int h0 = wid * 32 + (lane >> 3) * 4;        // 4 h
    float c[4][4] = {};

    const int c0 = ds * 2;                            // 2 chunks: c0, c0+1
    LOADX(c0); LOADW(c0);
    WRITE_LDS();

    for (int cc = 0; cc < 2; ++cc) {
        __syncthreads();                  // LDS chunk ready
        if (cc < 1) { LOADX(c0 + 1); LOADW(c0 + 1); }
#pragma unroll 8
        for (int kk = 0; kk < 64; ++kk) {
            const int xc = ((kk >> 2) & 7) << 2;
            float xr[4], wr[4];
            *(float4*)&xr[0] = *(const float4*)&Xs[kk * 32  + (r0 ^ xc)];
            *(float4*)&wr[0] = *(const float4*)&Ws[kk * 128 + (h0 ^ xc)];
#pragma unroll
            for (int i = 0; i < 4; ++i)
#pragma unroll
                for (int j = 0; j < 4; ++j) c[i][j] = fmaf(xr[i], wr[j], c[i][j]);
        }
        __syncthreads();                  // all reads done
        if (cc < 1) WRITE_LDS();
    }

    float* outp = psum + ((size_t)ds * 5120 + R0) * 128;
#pragma unroll
    for (int i = 0; i < 4; ++i)
        *(float4*)&outp[(size_t)(r0 + i) * 128 + h0] = *(const float4*)&c[i][0];

    #undef LOADX
    #undef LOADW
    #undef WRITE_LDS
}

// ---------------------------------------------------------------------------
// proj_reduce: sum 4 d-slices, then store eq = exp2(2*log2e * qh) and
// ek = exp2(2*log2e * kh)  (factored inner exponentials).  Grid 640.
// ---------------------------------------------------------------------------
__global__ __launch_bounds__(256) void proj_reduce(
    const float* __restrict__ psum, const int* __restrict__ valid_lens,
    float* __restrict__ qh_s, float4* __restrict__ kh4)
{
    int gid = blockIdx.x * 256 + threadIdx.x;    // [0, 163840)
    int row = gid >> 5, c4 = gid & 31;
    int b = 0, kk = 0;
    if (row >= 1024) {
        int r = row - 1024;
        b = r >> 10; kk = r & 1023;
        if (kk >= valid_lens[b]) return;
    }
    float4 s = make_float4(0.f, 0.f, 0.f, 0.f);
#pragma unroll
    for (int ds = 0; ds < 4; ++ds) {
        float4 v = *(const float4*)&psum[((size_t)ds * 5120 + row) * 128 + c4 * 4];
        s.x += v.x; s.y += v.y; s.z += v.z; s.w += v.w;
    }
    const float SC = 2.0f * LOG2E;
    s.x = __builtin_amdgcn_exp2f(s.x * SC);
    s.y = __builtin_amdgcn_exp2f(s.y * SC);
    s.z = __builtin_amdgcn_exp2f(s.z * SC);
    s.w = __builtin_amdgcn_exp2f(s.w * SC);
    if (row < 1024) *(float4*)&qh_s[(size_t)row * 128 + c4 * 4] = s;
    else            kh4[((size_t)(b * 32 + c4)) * K_ + kk] = s;
}

// ---------------------------------------------------------------------------
// attn_part: 2048 blocks x 256 thr (4 waves), item = (b, 8-q tile, 64-k
// chunk); ~1024 active.  LDS ~14.6 KB.
// Phase B: 4-way h-split (hh = wave, 8 hq each), ek prefetch depth 1,
// factored sigmoid: acc += w' * rcp(eq*ek + 1)  — 3 VALU + 1 trans / elem.
// Combine: all 4 waves, 2 q-rows each.
// Phase D: per-thread float2 column (256 cols) x 8 q-rows x full klen.
// ---------------------------------------------------------------------------
__global__ __launch_bounds__(256) void attn_part(
    const float* __restrict__ qh_s, const float4* __restrict__ kh4,
    const float* __restrict__ wvg,  const int* __restrict__ valid_lens,
    const float* __restrict__ vin,
    float* __restrict__ s_part, float* __restrict__ o_part)
{
    __shared__ float  qv[1024];
    __shared__ float  wvs[128];
    __shared__ float  ptmp[4][8][64];
    __shared__ float  p[8][64];
    __shared__ float  sred[8];

    const int t   = threadIdx.x;
    const int bid = blockIdx.x;
    const int qt  = bid & 31, kc = (bid >> 5) & 15, b = bid >> 9;
    const int q0  = qt * 8;
    const int vl  = valid_lens[b];
    const int kbase = kc * 64;
    if (kbase >= vl) return;
    const int klen = min(64, vl - kbase);

#pragma unroll
    for (int i = 0; i < 4; ++i)
        qv[t + i * 256] = qh_s[(size_t)(b*Q_ + q0) * H_ + t + i * 256];
    if (t < 128) wvs[t] = wvg[t] * (-2.0f * LOG2E);
    __syncthreads();

    const int k  = t & 63;              // k within chunk
    const int hh = t >> 6;              // h-quarter (== wave id)
    const bool active = k < klen;

    // ---- Phase B: scores (4-way h-split, ek prefetch depth 1) ----
    float acc[8] = {};
    if (active) {
        const float4* khp = kh4 + (size_t)b * 32 * K_ + (kbase + k)
                          + (size_t)(hh * 8) * K_;
        const int hq0 = hh * 8;
        float4 kxn = khp[0];
#pragma unroll
        for (int i = 0; i < 8; ++i) {
            float4 kx = kxn;
            int ni = (i < 7) ? i + 1 : 7;
            kxn = khp[(size_t)ni * K_];
            const int hq = hq0 + i;
            float w4[4], kxa[4];
            *(float4*)&w4[0]  = *(const float4*)&wvs[hq*4];
            *(float4*)&kxa[0] = kx;
#pragma unroll
            for (int qi = 0; qi < 8; ++qi) {
                float q4[4];
                *(float4*)&q4[0] = *(const float4*)&qv[qi*128 + hq*4];
#pragma unroll
                for (int j = 0; j < 4; ++j) {
                    float tt = q4[j] * kxa[j];          // eq * ek
                    float rr = __builtin_amdgcn_rcpf(tt + 1.0f);
                    acc[qi] = fmaf(w4[j], rr, acc[qi]);
                }
            }
        }
    }
#pragma unroll
    for (int qi = 0; qi < 8; ++qi) ptmp[hh][qi][k] = acc[qi];
    __syncthreads();

    // ---- combine: each wave finishes 2 q-rows ----
    {
        const int qia = hh * 2;
#pragma unroll
        for (int q2 = 0; q2 < 2; ++q2) {
            const int qi = qia + q2;
            float a = ptmp[0][qi][k] + ptmp[1][qi][k]
                    + ptmp[2][qi][k] + ptmp[3][qi][k];
            // a is already log2(p) (all scale factors folded upstream)
            float e = active ? __builtin_amdgcn_exp2f(a) : 0.f;
            p[qi][k] = e;
            float s = e;
#pragma unroll
            for (int off = 32; off > 0; off >>= 1) s += __shfl_xor(s, off);
            if (k == 0) sred[qi] = s;
        }
    }
    __syncthreads();                    // p + sred ready

    if (t < 8)
        s_part[(size_t)(b*Q_ + q0 + t) * 16 + kc] = sred[t];

    // ---- Phase D: partial PV (float2 col per thread, full klen) ----
    const int col2 = t;                 // float2 column 0..255
    const float2* vb2 = (const float2*)vin + ((size_t)b * K_ + kbase) * 256;

    float2 o[8];
#pragma unroll
    for (int qi = 0; qi < 8; ++qi) o[qi] = make_float2(0.f, 0.f);

    int kk = 0;
    const int nfull = klen >> 2;
    if (nfull > 0) {
        float2 n0v = vb2[(size_t)0 * 256 + col2];
        float2 n1v = vb2[(size_t)1 * 256 + col2];
        float2 n2v = vb2[(size_t)2 * 256 + col2];
        float2 n3v = vb2[(size_t)3 * 256 + col2];
        for (int g = 0; g < nfull; ++g) {
            float2 v0 = n0v, v1 = n1v, v2 = n2v, v3 = n3v;
            int kn = kk + 4;
            if (g + 1 < nfull) {
                n0v = vb2[(size_t)(kn+0)*256 + col2];
                n1v = vb2[(size_t)(kn+1)*256 + col2];
                n2v = vb2[(size_t)(kn+2)*256 + col2];
                n3v = vb2[(size_t)(kn+3)*256 + col2];
            }
#pragma unroll
            for (int qi = 0; qi < 8; ++qi) {
                float4 pq = *(const float4*)&p[qi][kk];   // uniform -> broadcast
                o[qi].x += pq.x*v0.x + pq.y*v1.x + pq.z*v2.x + pq.w*v3.x;
                o[qi].y += pq.x*v0.y + pq.y*v1.y + pq.z*v2.y + pq.w*v3.y;
            }
            kk = kn;
        }
    }
    for (; kk < klen; ++kk) {
        float2 v0 = vb2[(size_t)kk*256 + col2];
#pragma unroll
        for (int qi = 0; qi < 8; ++qi) {
            float pk = p[qi][kk];
            o[qi].x += pk*v0.x; o[qi].y += pk*v0.y;
        }
    }

#pragma unroll
    for (int qi = 0; qi < 8; ++qi) {
        size_t row = (size_t)b*Q_ + q0 + qi;
        *(float2*)&o_part[((size_t)kc * 1024 + row) * 512 + col2 * 2] = o[qi];
    }
}

// ---------------------------------------------------------------------------
// finalize: out[row][col] = (Sum_{ch<nch} o_part[ch][row][col]) * rcp(Sum s).
// nch = ceil(vl/64) <= 16.
// ---------------------------------------------------------------------------
__global__ __launch_bounds__(256) void finalize_kernel(
    const float4* __restrict__ o_part, const float* __restrict__ s_part,
    const int* __restrict__ valid_lens, float4* __restrict__ out)
{
    int gid = blockIdx.x * 256 + threadIdx.x;     // [0, 131072)
    int row = gid >> 7, col = gid & 127;
    int b = row >> 8;
    int nch = (valid_lens[b] + 63) >> 6;
    float ssum = 0.f;
    float4 o = make_float4(0.f, 0.f, 0.f, 0.f);
    for (int ch = 0; ch < nch; ++ch) {
        ssum += s_part[(size_t)row * 16 + ch];
        float4 r = o_part[((size_t)ch * 1024 + row) * 128 + col];
        o.x += r.x; o.y += r.y; o.z += r.z; o.w += r.w;
    }
    float rs = __builtin_amdgcn_rcpf(ssum);
    out[gid] = make_float4(o.x*rs, o.y*rs, o.z*rs, o.w*rs);
}

extern "C" void kernel_launch(void* const* d_in, const int* in_sizes, int n_in,
                              void* d_out, int out_size, void* d_ws, size_t ws_size,
                              hipStream_t stream)
{
    const float* q  = (const float*)d_in[0];
    const float* k  = (const float*)d_in[1];
    const float* v  = (const float*)d_in[2];
    const int*   vl = (const int*)d_in[3];
    const float* wq = (const float*)d_in[4];
    const float* wk = (const float*)d_in[5];
    const float* wv = (const float*)d_in[6];
    float* out = (float*)d_out;

    float* qh_s  = (float*)d_ws;                      //  131072 f
    float* kh4   = qh_s  + (size_t)B_*Q_*H_;          //  524288 f
    float* s_prt = kh4   + (size_t)B_*H_*K_;          //   16384 f
    float* o_prt = s_prt + (size_t)B_*Q_*16;          // 8388608 f (32 MB)
    float* psum  = o_prt + (size_t)16*B_*Q_*DV_;      // 2621440 f (10.5 MB)

    proj_part      <<<dim3(640),  dim3(256), 0, stream>>>(q, k, wq, wk, vl, psum);
    proj_reduce    <<<dim3(640),  dim3(256), 0, stream>>>(psum, vl, qh_s, (float4*)kh4);
    attn_part      <<<dim3(2048), dim3(256), 0, stream>>>(qh_s, (const float4*)kh4, wv, vl, v, s_prt, o_prt);
    finalize_kernel<<<dim3(512),  dim3(256), 0, stream>>>((const float4*)o_prt, s_prt, vl, (float4*)out);
}